// Round 2
// baseline (12724.061 us; speedup 1.0000x reference)
//
#include <hip/hip_runtime.h>
#include <math.h>

constexpr int kB = 256;
constexpr int kT = 200;
constexpr int kD = 512;
constexpr int kU = 1024;
constexpr int kG = 4096;   // 4*U

typedef short frag8 __attribute__((ext_vector_type(8)));     // 8 bf16 (4 VGPRs)
typedef float floatx4 __attribute__((ext_vector_type(4)));   // MFMA C/D frag
typedef unsigned short ushort_t;
typedef unsigned long long u64;

__device__ __forceinline__ ushort_t f2bf(float f) {
    union { float f; unsigned int u; } v; v.f = f;
    unsigned int r = v.u + 0x7fffu + ((v.u >> 16) & 1u);   // RNE
    return (ushort_t)(r >> 16);
}
__device__ __forceinline__ float bf2f(ushort_t h) {
    union { unsigned int u; float f; } v; v.u = ((unsigned int)h) << 16;
    return v.f;
}

// ---------------------------------------------------------------------------
// Repack [W (K1 rows); Uw (K-K1 rows)] fp32 [*,4096] -> bf16 fragment order.
// Gate-interleaved columns: n_new = 4*j + g  <->  n_old = g*1024 + j.
// frag8 addr (units): ((nb*nkb + kb)*4 + ct)*64 + lane  (verified, absmax 0.0)
// ---------------------------------------------------------------------------
__global__ __launch_bounds__(256)
void repack_weights(const float* __restrict__ W, const float* __restrict__ Uw,
                    int K1, int K, ushort_t* __restrict__ out)
{
    const int nkb = K >> 5;
    const int kb = blockIdx.x % nkb;
    const int nb = blockIdx.x / nkb;
    __shared__ ushort_t tile[2048];
    const int tid = threadIdx.x;
#pragma unroll
    for (int i = 0; i < 8; i++) {
        int idx  = tid + (i << 8);         // 0..2047
        int kl   = idx >> 6;               // 0..31
        int lcol = idx & 63;               // 0..63
        int g  = lcol >> 4;
        int jl = lcol & 15;
        int k  = (kb << 5) + kl;
        int n_old = (g << 10) + (nb << 4) + jl;
        float v = (k < K1) ? W[(long)k * kG + n_old]
                           : Uw[(long)(k - K1) * kG + n_old];
        int n_new_l = (jl << 2) + g;       // local packed column
        int ng = n_new_l >> 4, nl = n_new_l & 15;
        int quad = kl >> 3, e = kl & 7;
        tile[ng * 512 + (quad * 16 + nl) * 8 + e] = f2bf(v);
    }
    __syncthreads();
    long base = ((long)(nb * nkb + kb)) * 2048;
    *(frag8*)&out[base + tid * 8] = *(frag8*)&tile[tid * 8];
}

__global__ __launch_bounds__(256)
void repack_bias(const float* __restrict__ b1, const float* __restrict__ b2,
                 float* __restrict__ o1, float* __restrict__ o2)
{
    int n = blockIdx.x * blockDim.x + threadIdx.x;   // 0..4095
    int n_old = ((n & 3) << 10) + (n >> 2);
    o1[n] = b1[n_old];
    o2[n] = b2[n_old];
}

// One-time embedding gather + fp32->bf16: xbf[b*T+t][d].
__global__ __launch_bounds__(128)
void xgather(const int* __restrict__ tokens, const float* __restrict__ emb,
             ushort_t* __restrict__ xbf)
{
    int bt = blockIdx.x;
    int tok = tokens[bt];
    float4 v = *(const float4*)(emb + (long)tok * kD + threadIdx.x * 4);
    unsigned int lo = ((unsigned int)f2bf(v.y) << 16) | f2bf(v.x);
    unsigned int hi = ((unsigned int)f2bf(v.w) << 16) | f2bf(v.z);
    uint2 p; p.x = lo; p.y = hi;
    *(uint2*)(xbf + (long)bt * kD + threadIdx.x * 4) = p;
}

// ---------------------------------------------------------------------------
// Persistent weight-resident LSTM, fence-free.
// 256 blocks x 512 thr (8 waves, 1 block/CU pinned by ~146KB LDS).
// Blocks 0..127 = layer2 (K=2048), 128..255 = layer1 (K=1536). Each block owns
// 32 packed gate-cols (8 h units), stages its weight slice to LDS once.
// h cross-block traffic: writes = plain stores flushed by RELEASE arrival
// (buffer_wbl2); reads = agent-scope RELAXED atomic loads (coherent bypass).
// NO acquire fences -> x/weights stay L2-cached, no inv storms.
// Two independent 128-block epoch barriers; h buffers rotate R=4 so layer1
// runs ahead of layer2 (critical path = layer2 chain only).
// Wave tile 32 rows x 32 cols (acc[2][2]); c-state in registers all 200 steps.
// Same per-element K accumulation order as before -> bitwise-identical output.
// ---------------------------------------------------------------------------
struct Batch { frag8 A[8]; frag8 B[8]; };

__device__ __forceinline__ frag8 loadA_bypass(const ushort_t* p) {
    union { frag8 f; u64 u[2]; } r;
    r.u[0] = __hip_atomic_load((const u64*)p,     __ATOMIC_RELAXED, __HIP_MEMORY_SCOPE_AGENT);
    r.u[1] = __hip_atomic_load((const u64*)p + 1, __ATOMIC_RELAXED, __HIP_MEMORY_SCOPE_AGENT);
    return r.f;
}

template<int K1KB, bool PLAIN1>
__device__ __forceinline__ void load_batch(int bi, Batch& bb,
    const ushort_t* const (&a1p)[2], const ushort_t* const (&a2p)[2],
    const frag8* __restrict__ wl)
{
    const int kb0 = bi * 4;
#pragma unroll
    for (int u = 0; u < 4; u++) {
        bb.B[u*2+0] = wl[((kb0+u)*2+0) * 64];
        bb.B[u*2+1] = wl[((kb0+u)*2+1) * 64];
    }
    if (kb0 < K1KB) {      // batches are 4-kb aligned; K1KB % 4 == 0
#pragma unroll
        for (int u = 0; u < 4; u++)
#pragma unroll
            for (int i = 0; i < 2; i++) {
                if (PLAIN1)
                    bb.A[u*2+i] = *(const frag8*)(a1p[i] + (kb0+u) * 32);
                else
                    bb.A[u*2+i] = loadA_bypass(a1p[i] + (kb0+u) * 32);
            }
    } else {
#pragma unroll
        for (int u = 0; u < 4; u++)
#pragma unroll
            for (int i = 0; i < 2; i++)
                bb.A[u*2+i] = loadA_bypass(a2p[i] + (kb0+u-K1KB) * 32);
    }
}

__device__ __forceinline__ void mfma_batch(const Batch& bb, floatx4 (&acc)[2][2])
{
#pragma unroll
    for (int u = 0; u < 4; u++)
#pragma unroll
        for (int mi = 0; mi < 2; mi++)
#pragma unroll
            for (int ct = 0; ct < 2; ct++)
                acc[mi][ct] = __builtin_amdgcn_mfma_f32_16x16x32_bf16(
                    bb.A[u*2+mi], bb.B[u*2+ct], acc[mi][ct], 0, 0, 0);
}

__device__ __forceinline__ void wait_flag(const int* f, int need) {
    if (need <= 0) return;
    while (__hip_atomic_load(f, __ATOMIC_RELAXED, __HIP_MEMORY_SCOPE_AGENT) < need)
        __builtin_amdgcn_s_sleep(4);
}

__device__ __forceinline__ void arrive(int* cnt, int* flag, int stepdone) {
    // RELEASE fetch_add: buffer_wbl2 flushes this XCD's dirty h lines to L3
    int old = __hip_atomic_fetch_add(cnt, 1, __ATOMIC_RELEASE, __HIP_MEMORY_SCOPE_AGENT);
    if (old == 128 * stepdone - 1)
        __hip_atomic_store(flag, stepdone, __ATOMIC_RELEASE, __HIP_MEMORY_SCOPE_AGENT);
}

template<int NKB, int K1KB, bool PLAIN1>
__device__ __forceinline__ void step_block(
    const ushort_t* __restrict__ A1, long a1_rs, long a1_off,
    const ushort_t* __restrict__ A2,              // row stride kU
    const ushort_t* __restrict__ wlds_,
    float4 bias4, float (&creg)[2][2],
    ushort_t* __restrict__ hOut, int ub, float* __restrict__ zsw)
{
    const int tid = threadIdx.x, lane = tid & 63, wave = tid >> 6;
    const int wrow = wave << 5;                    // wave owns 32 rows
    const int r0 = wrow + (lane & 15);
    const int kq = (lane >> 4) << 3;

    const ushort_t* a1p[2]; const ushort_t* a2p[2];
#pragma unroll
    for (int i = 0; i < 2; i++) {
        a1p[i] = A1 + (long)(r0 + 16*i) * a1_rs + a1_off + kq;
        a2p[i] = A2 + (long)(r0 + 16*i) * kU + kq;
    }
    const frag8* wl = (const frag8*)wlds_ + lane;

    floatx4 acc[2][2];
#pragma unroll
    for (int i = 0; i < 2; i++) {
        acc[i][0] = (floatx4){0.f,0.f,0.f,0.f};
        acc[i][1] = (floatx4){0.f,0.f,0.f,0.f};
    }

    constexpr int NBATCH = NKB / 4;                // 16 (L2) or 12 (L1) — even
    Batch X, Y;
    load_batch<K1KB,PLAIN1>(0, X, a1p, a2p, wl);
#pragma unroll 1
    for (int bi = 0; bi < NBATCH; bi += 2) {
        load_batch<K1KB,PLAIN1>(bi + 1, Y, a1p, a2p, wl);
        mfma_batch(X, acc);
        if (bi + 2 < NBATCH) load_batch<K1KB,PLAIN1>(bi + 2, X, a1p, a2p, wl);
        mfma_batch(Y, acc);
    }

    // Epilogue: per-wave LDS transpose (intra-wave DS FIFO ordering), fp32 gates.
    const int q = lane >> 4, c16 = lane & 15;
    const int rl0 = lane >> 3, jl = lane & 7;      // jl constant per lane
#pragma unroll
    for (int mi = 0; mi < 2; mi++) {
#pragma unroll
        for (int ct = 0; ct < 2; ct++)
#pragma unroll
            for (int r = 0; r < 4; r++)
                zsw[((q << 2) + r) * 36 + (ct << 4) + c16] = acc[mi][ct][r];
#pragma unroll
        for (int ii = 0; ii < 2; ii++) {
            int rowl = rl0 + (ii << 3);
            float4 z4 = *(float4*)&zsw[rowl * 36 + (jl << 2)];
            float zi = z4.x + bias4.x, zf = z4.y + bias4.y;
            float zg = z4.z + bias4.z, zo = z4.w + bias4.w;
            float ig = 1.f / (1.f + __expf(-zi));
            float fg = 1.f / (1.f + __expf(-zf));
            float og = 1.f / (1.f + __expf(-zo));
            float gg = 1.f - 2.f / (__expf(2.f * zg) + 1.f);   // tanh
            float cn = fg * creg[mi][ii] + ig * gg;
            creg[mi][ii] = cn;
            float tc = 1.f - 2.f / (__expf(2.f * cn) + 1.f);   // tanh
            int m = wrow + (mi << 4) + rowl;
            hOut[(long)m * kU + ub + jl] = f2bf(og * tc);
        }
    }
}

__global__ __launch_bounds__(512, 1)
void lstm_persist(const ushort_t* __restrict__ W1p, const ushort_t* __restrict__ W2p,
                  const float* __restrict__ b1p, const float* __restrict__ b2p,
                  const ushort_t* __restrict__ xbf,
                  ushort_t* __restrict__ h1bufs,   // 4 x [kB*kU] rotating
                  ushort_t* __restrict__ h2bufs,   // 4 x [kB*kU] rotating
                  int* __restrict__ sync)          // [0]=ecnt1 [32]=eflag1 [64]=ecnt2 [96]=eflag2
{
    __shared__ __align__(16) ushort_t wlds[65536];   // 128 KB weight slice
    __shared__ __align__(16) float zs[8][576];       // 18 KB epilogue transpose

    const int bid = blockIdx.x;
    const bool isL2 = bid < 128;
    const int b = isL2 ? bid : bid - 128;            // owns packed cols [32b, 32b+32)
    const int tid = threadIdx.x, lane = tid & 63, wave = tid >> 6;

    // ---- one-time: stage weight slice into LDS ----
    {
        const frag8* wg = (const frag8*)(isL2 ? W2p : W1p);
        const int NKB = isL2 ? 64 : 48;
        const int nb2 = b >> 1, cbase = (b & 1) * 2;
        const long gb = (long)nb2 * NKB * 256;       // frag8 units
        frag8* wl = (frag8*)wlds;
        for (int i = tid; i < NKB * 128; i += 512) {
            int kb = i >> 7, r = i & 127;
            wl[i] = wg[gb + ((long)kb * 4 + cbase + (r >> 6)) * 64 + (r & 63)];
        }
    }

    const float4* biasP4 = (const float4*)(isL2 ? b2p : b1p);
    const float4 bias4 = biasP4[b * 8 + (lane & 7)]; // this lane's 4 gate biases

    float creg[2][2];                                // c-state: 4 fp32/lane, whole seq
    creg[0][0] = creg[0][1] = creg[1][0] = creg[1][1] = 0.f;

    float* zsw = zs[wave];
    const int ub = b << 3;                           // h-unit column base
    int* ecnt1  = sync;      int* eflag1 = sync + 32;
    int* ecnt2  = sync + 64; int* eflag2 = sync + 96;
    const size_t SZ = (size_t)kB * kU;

    __syncthreads();                                 // weights staged

    if (isL2) {
#pragma unroll 1
        for (int s = 0; s < kT; s++) {
            // h1[s] ready (eflag1>=s+1); all L2 peers done step s-1 (eflag2>=s)
            if (tid == 0) { wait_flag(eflag1, s + 1); wait_flag(eflag2, s); }
            __syncthreads();
            step_block<64, 32, false>(h1bufs + ((s + 1) & 3) * SZ, kU, 0,
                                      h2bufs + (s & 3) * SZ, wlds,
                                      bias4, creg,
                                      h2bufs + ((s + 1) & 3) * SZ, ub, zsw);
            __syncthreads();                         // all waves' stores drained
            if (tid == 0) arrive(ecnt2, eflag2, s + 1);
        }
    } else {
#pragma unroll 1
        for (int t = 0; t < kT; t++) {
            // h1[t-1] ready (eflag1>=t); layer2 within 2 steps (buffer reuse guard)
            if (tid == 0) { wait_flag(eflag1, t); wait_flag(eflag2, t - 2); }
            __syncthreads();
            step_block<48, 16, true>(xbf, (long)kT * kD, (long)t * kD,
                                     h1bufs + (t & 3) * SZ, wlds,
                                     bias4, creg,
                                     h1bufs + ((t + 1) & 3) * SZ, ub, zsw);
            __syncthreads();
            if (tid == 0) arrive(ecnt1, eflag1, t + 1);
        }
    }
}

// out[b] = sigmoid(h[b,:] . Wfc + bfc), h in bf16
__global__ __launch_bounds__(256)
void fc_sigmoid(const ushort_t* __restrict__ h, const float* __restrict__ Wfc,
                const float* __restrict__ bfc, float* __restrict__ out)
{
    int b = blockIdx.x, tid = threadIdx.x;
    float s = 0.f;
    for (int j = tid; j < kU; j += 256) s += bf2f(h[(long)b * kU + j]) * Wfc[j];
    __shared__ float red[4];
    for (int off = 32; off > 0; off >>= 1) s += __shfl_down(s, off, 64);
    if ((tid & 63) == 0) red[tid >> 6] = s;
    __syncthreads();
    if (tid == 0) {
        float t = red[0] + red[1] + red[2] + red[3] + bfc[0];
        out[b] = 1.f / (1.f + expf(-t));
    }
}

extern "C" void kernel_launch(void* const* d_in, const int* in_sizes, int n_in,
                              void* d_out, int out_size, void* d_ws, size_t ws_size,
                              hipStream_t stream)
{
    (void)in_sizes; (void)n_in; (void)out_size; (void)ws_size;

    const int*   tokens = (const int*)d_in[0];
    const float* emb    = (const float*)d_in[1];
    const float* W1     = (const float*)d_in[2];
    const float* U1     = (const float*)d_in[3];
    const float* b1     = (const float*)d_in[4];
    const float* W2     = (const float*)d_in[5];
    const float* U2     = (const float*)d_in[6];
    const float* b2     = (const float*)d_in[7];
    const float* Wfc    = (const float*)d_in[8];
    const float* bfc    = (const float*)d_in[9];
    float* out = (float*)d_out;

    // Workspace: ~86 MB
    ushort_t* W1p = (ushort_t*)d_ws;                       // [1536*4096] bf16
    ushort_t* W2p = W1p + (size_t)1536 * kG;               // [2048*4096] bf16
    float* b1p = (float*)(W2p + (size_t)2048 * kG);        // [4096] f32
    float* b2p = b1p + kG;                                 // [4096] f32
    ushort_t* h1bufs = (ushort_t*)(b2p + kG);              // 4 x [256*1024] bf16
    ushort_t* h2bufs = h1bufs + 4 * (size_t)kB * kU;       // 4 x [256*1024] bf16
    int* sync = (int*)(h2bufs + 4 * (size_t)kB * kU);      // 128 ints (512 B)
    ushort_t* xbf = (ushort_t*)(sync + 128);               // [B*T*512] bf16

    repack_weights<<<48 * 64, 256, 0, stream>>>(W1, U1, 512, 1536, W1p);
    repack_weights<<<64 * 64, 256, 0, stream>>>(W2, U2, 1024, 2048, W2p);
    repack_bias<<<16, 256, 0, stream>>>(b1, b2, b1p, b2p);
    xgather<<<kB * kT, 128, 0, stream>>>(tokens, emb, xbf);
    // zero h buffers (bf16) + sync area: contiguous 4 MB + 512 B
    hipMemsetAsync(h1bufs, 0, 8 * (size_t)kB * kU * sizeof(ushort_t) + 512, stream);

    void* args[] = { &W1p, &W2p, &b1p, &b2p, &xbf, &h1bufs, &h2bufs, &sync };
    hipLaunchCooperativeKernel((void*)lstm_persist, dim3(256), dim3(512),
                               args, 0, stream);

    // layer2 output of step s=199 lands in h2bufs[(199+1)&3] = buf 0
    fc_sigmoid<<<kB, 256, 0, stream>>>(h2bufs, Wfc, bfc, out);
}

// Round 3
// 8166.190 us; speedup vs baseline: 1.5581x; 1.5581x over previous
//
#include <hip/hip_runtime.h>
#include <math.h>

constexpr int kB = 256;
constexpr int kT = 200;
constexpr int kD = 512;
constexpr int kU = 1024;
constexpr int kG = 4096;   // 4*U

typedef short frag8 __attribute__((ext_vector_type(8)));     // 8 bf16 (4 VGPRs)
typedef float floatx4 __attribute__((ext_vector_type(4)));   // MFMA C/D frag
typedef unsigned short ushort_t;

__device__ __forceinline__ ushort_t f2bf(float f) {
    union { float f; unsigned int u; } v; v.f = f;
    unsigned int r = v.u + 0x7fffu + ((v.u >> 16) & 1u);   // RNE
    return (ushort_t)(r >> 16);
}
__device__ __forceinline__ float bf2f(ushort_t h) {
    union { unsigned int u; float f; } v; v.u = ((unsigned int)h) << 16;
    return v.f;
}

// ---------------------------------------------------------------------------
// Repack [W (K1 rows); Uw (K-K1 rows)] fp32 [*,4096] -> bf16 fragment order.
// Gate-interleaved columns: n_new = 4*j + g  <->  n_old = g*1024 + j.
// frag8 addr (units): ((nb*nkb + kb)*4 + ct)*64 + lane  (verified, absmax 0.0)
// ---------------------------------------------------------------------------
__global__ __launch_bounds__(256)
void repack_weights(const float* __restrict__ W, const float* __restrict__ Uw,
                    int K1, int K, ushort_t* __restrict__ out)
{
    const int nkb = K >> 5;
    const int kb = blockIdx.x % nkb;
    const int nb = blockIdx.x / nkb;
    __shared__ ushort_t tile[2048];
    const int tid = threadIdx.x;
#pragma unroll
    for (int i = 0; i < 8; i++) {
        int idx  = tid + (i << 8);         // 0..2047
        int kl   = idx >> 6;               // 0..31
        int lcol = idx & 63;               // 0..63
        int g  = lcol >> 4;
        int jl = lcol & 15;
        int k  = (kb << 5) + kl;
        int n_old = (g << 10) + (nb << 4) + jl;
        float v = (k < K1) ? W[(long)k * kG + n_old]
                           : Uw[(long)(k - K1) * kG + n_old];
        int n_new_l = (jl << 2) + g;       // local packed column
        int ng = n_new_l >> 4, nl = n_new_l & 15;
        int quad = kl >> 3, e = kl & 7;
        tile[ng * 512 + (quad * 16 + nl) * 8 + e] = f2bf(v);
    }
    __syncthreads();
    long base = ((long)(nb * nkb + kb)) * 2048;
    *(frag8*)&out[base + tid * 8] = *(frag8*)&tile[tid * 8];
}

__global__ __launch_bounds__(256)
void repack_bias(const float* __restrict__ b1, const float* __restrict__ b2,
                 float* __restrict__ o1, float* __restrict__ o2)
{
    int n = blockIdx.x * blockDim.x + threadIdx.x;   // 0..4095
    int n_old = ((n & 3) << 10) + (n >> 2);
    o1[n] = b1[n_old];
    o2[n] = b2[n_old];
}

// One-time embedding gather + fp32->bf16: xbf[b*T+t][d].
__global__ __launch_bounds__(128)
void xgather(const int* __restrict__ tokens, const float* __restrict__ emb,
             ushort_t* __restrict__ xbf)
{
    int bt = blockIdx.x;
    int tok = tokens[bt];
    float4 v = *(const float4*)(emb + (long)tok * kD + threadIdx.x * 4);
    unsigned int lo = ((unsigned int)f2bf(v.y) << 16) | f2bf(v.x);
    unsigned int hi = ((unsigned int)f2bf(v.w) << 16) | f2bf(v.z);
    uint2 p; p.x = lo; p.y = hi;
    *(uint2*)(xbf + (long)bt * kD + threadIdx.x * 4) = p;
}

// ---------------------------------------------------------------------------
// Per-step kernel, B staged through LDS (read weights ONCE per block per step).
// Grid (64,1,2) x 512 thr. Block = 64 packed cols (nb2 = blockIdx.x) x all 256
// rows; 8 waves = 8 row-groups of 32 rows, wave tile 32x64 (acc[2][4] — round-0
// verified tile + epilogue). K-loop: chunks of 4 kb (128 k); per chunk the
// block stages a contiguous 16 KB weight slab global->reg->LDS (double-
// buffered, one barrier/iter) while A-frags for the next chunk prefetch into
// registers. Weight traffic drops 8x vs per-wave L2 reads; weight panels stay
// XCD-resident (block b -> XCD b%8, stable across the 201 dispatches).
// Same per-element kb accumulation order as round 0 -> bitwise-identical.
// ---------------------------------------------------------------------------
template<int NKB, int K1KB>
__device__ __forceinline__ void step_core(
    const ushort_t* __restrict__ A1, long a1_rs, long a1_off,
    const ushort_t* __restrict__ A2,              // row stride kU
    const ushort_t* __restrict__ Wp,
    const float4* __restrict__ biasP4,
    float* __restrict__ cSt, ushort_t* __restrict__ hOut,
    ushort_t* __restrict__ bl, float* __restrict__ zsw)
{
    const int tid  = threadIdx.x;
    const int lane = tid & 63;
    const int wave = tid >> 6;                     // row-group 0..7
    const int nb2  = blockIdx.x;                   // 64-col superblock 0..63
    const int wrow = wave << 5;                    // 32 rows per wave
    const int kq   = (lane >> 4) << 3;
    const int r0   = wrow + (lane & 15);

    const ushort_t* a1p0 = A1 + (long)r0 * a1_rs + a1_off + kq;
    const ushort_t* a1p1 = A1 + (long)(r0 + 16) * a1_rs + a1_off + kq;
    const ushort_t* a2p0 = A2 + (long)r0 * kU + kq;
    const ushort_t* a2p1 = A2 + (long)(r0 + 16) * kU + kq;

    // weights for this nb2: NKB*2048 ushorts, chunk c = 8192 ushorts (16 KB)
    const ushort_t* Wg = Wp + (long)nb2 * NKB * 2048;
    constexpr int NCH = NKB / 4;                   // 16 (L2) / 12 (L1) — even

    floatx4 acc[2][4];
#pragma unroll
    for (int i = 0; i < 2; i++)
#pragma unroll
        for (int j = 0; j < 4; j++) acc[i][j] = (floatx4){0.f, 0.f, 0.f, 0.f};

    auto ldA = [&](int ch, frag8 (&d)[8]) {
        const int kb0 = ch * 4;
        if (kb0 < K1KB) {                          // chunks are 4-kb aligned
#pragma unroll
            for (int u = 0; u < 4; u++) {
                d[u*2+0] = *(const frag8*)(a1p0 + (kb0 + u) * 32);
                d[u*2+1] = *(const frag8*)(a1p1 + (kb0 + u) * 32);
            }
        } else {
#pragma unroll
            for (int u = 0; u < 4; u++) {
                d[u*2+0] = *(const frag8*)(a2p0 + (kb0 - K1KB + u) * 32);
                d[u*2+1] = *(const frag8*)(a2p1 + (kb0 - K1KB + u) * 32);
            }
        }
    };

    auto one = [&](int ch, frag8 (&cur)[8], frag8 (&nxt)[8]) {
        const int p = ch & 1;
        const bool pf = (ch + 1 < NCH);
        frag8 g0, g1;
        if (pf) {                                  // issue next-chunk global loads
            const ushort_t* gs = Wg + (long)(ch + 1) * 8192 + tid * 16;
            g0 = *(const frag8*)gs;
            g1 = *(const frag8*)(gs + 8);
            ldA(ch + 1, nxt);
        }
        const ushort_t* bp = bl + p * 8192;        // compute chunk ch from LDS
#pragma unroll
        for (int kbl = 0; kbl < 4; kbl++) {
            frag8 b0 = *(const frag8*)&bp[((kbl*4+0)*64 + lane) * 8];
            frag8 b1 = *(const frag8*)&bp[((kbl*4+1)*64 + lane) * 8];
            frag8 b2 = *(const frag8*)&bp[((kbl*4+2)*64 + lane) * 8];
            frag8 b3 = *(const frag8*)&bp[((kbl*4+3)*64 + lane) * 8];
#pragma unroll
            for (int mi = 0; mi < 2; mi++) {
                acc[mi][0] = __builtin_amdgcn_mfma_f32_16x16x32_bf16(cur[kbl*2+mi], b0, acc[mi][0], 0, 0, 0);
                acc[mi][1] = __builtin_amdgcn_mfma_f32_16x16x32_bf16(cur[kbl*2+mi], b1, acc[mi][1], 0, 0, 0);
                acc[mi][2] = __builtin_amdgcn_mfma_f32_16x16x32_bf16(cur[kbl*2+mi], b2, acc[mi][2], 0, 0, 0);
                acc[mi][3] = __builtin_amdgcn_mfma_f32_16x16x32_bf16(cur[kbl*2+mi], b3, acc[mi][3], 0, 0, 0);
            }
        }
        if (pf) {                                  // write next chunk to other buf
            *(frag8*)&bl[(p ^ 1) * 8192 + tid * 16]     = g0;
            *(frag8*)&bl[(p ^ 1) * 8192 + tid * 16 + 8] = g1;
        }
        __syncthreads();
    };

    // prologue: stage chunk 0, prefetch A chunk 0
    frag8 aX[8], aY[8];
    {
        const ushort_t* gs = Wg + tid * 16;
        frag8 g0 = *(const frag8*)gs;
        frag8 g1 = *(const frag8*)(gs + 8);
        ldA(0, aX);
        *(frag8*)&bl[tid * 16]     = g0;
        *(frag8*)&bl[tid * 16 + 8] = g1;
    }
    __syncthreads();

#pragma unroll 1
    for (int c = 0; c < NCH; c += 2) {
        one(c,     aX, aY);
        one(c + 1, aY, aX);
    }

    // Epilogue: per-wave LDS transpose (intra-wave DS ordering), gates fp32.
    const int q = lane >> 4, c16 = lane & 15;
#pragma unroll 1
    for (int mi = 0; mi < 2; mi++) {
#pragma unroll
        for (int ct = 0; ct < 4; ct++)
#pragma unroll
            for (int r = 0; r < 4; r++)
                zsw[((q << 2) + r) * 68 + (ct << 4) + c16] = acc[mi][ct][r];
#pragma unroll
        for (int ii = 0; ii < 4; ii++) {
            int cell = lane + (ii << 6);
            int rowl = cell >> 4, jl = cell & 15;
            float4 z4 = *(float4*)&zsw[rowl * 68 + (jl << 2)];
            float4 bv = biasP4[(nb2 << 4) + jl];
            float zi = z4.x + bv.x, zf = z4.y + bv.y;
            float zg = z4.z + bv.z, zo = z4.w + bv.w;
            float ig = 1.f / (1.f + __expf(-zi));
            float fg = 1.f / (1.f + __expf(-zf));
            float og = 1.f / (1.f + __expf(-zo));
            float gg = 1.f - 2.f / (__expf(2.f * zg) + 1.f);   // tanh
            int m = wrow + (mi << 4) + rowl;
            long ci = (long)m * kU + (nb2 << 4) + jl;
            float cn = fg * cSt[ci] + ig * gg;
            float tc = 1.f - 2.f / (__expf(2.f * cn) + 1.f);   // tanh
            cSt[ci] = cn;
            hOut[ci] = f2bf(og * tc);
        }
    }
}

// grid (64, 1, 2): z=0 -> layer2 step t2=l-1, z=1 -> layer1 step t1=l
__global__ __launch_bounds__(512, 2)
void lstm_merged(int zmask,
    const ushort_t* h1_for2, const ushort_t* h2prev, const ushort_t* W2p,
    const float* b2p, float* c2, ushort_t* h2out,
    const ushort_t* xbf, int t1,
    const ushort_t* h1prev, const ushort_t* W1p,
    const float* b1p, float* c1, ushort_t* h1out)
{
    __shared__ __align__(16) ushort_t bl[16384];   // 32 KB B double-buffer
    __shared__ __align__(16) float zs[8][1088];    // 34 KB epilogue transpose
    float* zsw = zs[threadIdx.x >> 6];
    if (blockIdx.z == 0) {
        if (!(zmask & 1)) return;
        step_core<64, 32>(h1_for2, kU, 0, h2prev, W2p,
                          (const float4*)b2p, c2, h2out, bl, zsw);
    } else {
        if (!(zmask & 2)) return;
        step_core<48, 16>(xbf, (long)kT * kD, (long)t1 * kD, h1prev, W1p,
                          (const float4*)b1p, c1, h1out, bl, zsw);
    }
}

// out[b] = sigmoid(h[b,:] . Wfc + bfc), h in bf16
__global__ __launch_bounds__(256)
void fc_sigmoid(const ushort_t* __restrict__ h, const float* __restrict__ Wfc,
                const float* __restrict__ bfc, float* __restrict__ out)
{
    int b = blockIdx.x, tid = threadIdx.x;
    float s = 0.f;
    for (int j = tid; j < kU; j += 256) s += bf2f(h[(long)b * kU + j]) * Wfc[j];
    __shared__ float red[4];
    for (int off = 32; off > 0; off >>= 1) s += __shfl_down(s, off, 64);
    if ((tid & 63) == 0) red[tid >> 6] = s;
    __syncthreads();
    if (tid == 0) {
        float t = red[0] + red[1] + red[2] + red[3] + bfc[0];
        out[b] = 1.f / (1.f + expf(-t));
    }
}

extern "C" void kernel_launch(void* const* d_in, const int* in_sizes, int n_in,
                              void* d_out, int out_size, void* d_ws, size_t ws_size,
                              hipStream_t stream)
{
    (void)in_sizes; (void)n_in; (void)out_size; (void)ws_size;

    const int*   tokens = (const int*)d_in[0];
    const float* emb    = (const float*)d_in[1];
    const float* W1     = (const float*)d_in[2];
    const float* U1     = (const float*)d_in[3];
    const float* b1     = (const float*)d_in[4];
    const float* W2     = (const float*)d_in[5];
    const float* U2     = (const float*)d_in[6];
    const float* b2     = (const float*)d_in[7];
    const float* Wfc    = (const float*)d_in[8];
    const float* bfc    = (const float*)d_in[9];
    float* out = (float*)d_out;

    // Workspace: ~86 MB
    ushort_t* W1p = (ushort_t*)d_ws;                       // [1536*4096] bf16
    ushort_t* W2p = W1p + (size_t)1536 * kG;               // [2048*4096] bf16
    float* b1p = (float*)(W2p + (size_t)2048 * kG);        // [4096] f32
    float* b2p = b1p + kG;                                 // [4096] f32
    float* c1  = b2p + kG;                                 // [256*1024] f32
    float* c2  = c1 + (size_t)kB * kU;
    ushort_t* hbuf = (ushort_t*)(c2 + (size_t)kB * kU);    // 4 x [256*1024] bf16
    ushort_t* h1b[2] = { hbuf, hbuf + (size_t)kB * kU };
    ushort_t* h2b[2] = { hbuf + 2 * (size_t)kB * kU, hbuf + 3 * (size_t)kB * kU };
    ushort_t* xbf = hbuf + 4 * (size_t)kB * kU;            // [B*T*512] bf16

    repack_weights<<<48 * 64, 256, 0, stream>>>(W1, U1, 512, 1536, W1p);
    repack_weights<<<64 * 64, 256, 0, stream>>>(W2, U2, 1024, 2048, W2p);
    repack_bias<<<16, 256, 0, stream>>>(b1, b2, b1p, b2p);
    xgather<<<kB * kT, 128, 0, stream>>>(tokens, emb, xbf);
    // zero c1,c2 (fp32) + all h buffers (bf16): contiguous 4 MB
    hipMemsetAsync(c1, 0, (size_t)kB * kU * (2 * 4 + 4 * 2), stream);

    for (int l = 0; l <= kT; l++) {
        int t2 = l - 1, t1 = l;
        int zmask = (t2 >= 0 ? 1 : 0) | (t1 < kT ? 2 : 0);
        lstm_merged<<<dim3(64, 1, 2), 512, 0, stream>>>(zmask,
            h1b[(t2 + 1) & 1], h2b[t2 & 1], W2p, b2p, c2, h2b[(t2 + 1) & 1],
            xbf, t1, h1b[t1 & 1], W1p, b1p, c1, h1b[(t1 + 1) & 1]);
    }

    fc_sigmoid<<<kB, 256, 0, stream>>>(h2b[0], Wfc, bfc, out);
}

// Round 4
// 7457.327 us; speedup vs baseline: 1.7062x; 1.0951x over previous
//
#include <hip/hip_runtime.h>
#include <math.h>

constexpr int kB = 256;
constexpr int kT = 200;
constexpr int kD = 512;
constexpr int kU = 1024;
constexpr int kG = 4096;   // 4*U

typedef short frag8 __attribute__((ext_vector_type(8)));     // 8 bf16 (4 VGPRs)
typedef float floatx4 __attribute__((ext_vector_type(4)));   // MFMA C/D frag
typedef unsigned short ushort_t;

typedef __attribute__((address_space(1))) const unsigned int as1_uint;
typedef __attribute__((address_space(3))) unsigned int as3_uint;

__device__ __forceinline__ ushort_t f2bf(float f) {
    union { float f; unsigned int u; } v; v.f = f;
    unsigned int r = v.u + 0x7fffu + ((v.u >> 16) & 1u);   // RNE
    return (ushort_t)(r >> 16);
}
__device__ __forceinline__ float bf2f(ushort_t h) {
    union { unsigned int u; float f; } v; v.u = ((unsigned int)h) << 16;
    return v.f;
}

// global -> LDS direct copy, 16B per lane. LDS dest = wave-uniform base +
// lane*16 (per-lane l pointer is consistent: firstlane(l) = wave base).
__device__ __forceinline__ void gl_lds16(const ushort_t* g, ushort_t* l) {
    __builtin_amdgcn_global_load_lds((as1_uint*)g, (as3_uint*)l, 16, 0, 0);
}

// ---------------------------------------------------------------------------
// Repack [W (K1 rows); Uw (K-K1 rows)] fp32 [*,4096] -> bf16 fragment order.
// Gate-interleaved columns: n_new = 4*j + g  <->  n_old = g*1024 + j.
// frag8 addr (units): ((nb*nkb + kb)*4 + ct)*64 + lane  (verified, absmax 0.0)
// For each 64-col supergroup nb, a 4-kb chunk (16 KB) is CONTIGUOUS.
// ---------------------------------------------------------------------------
__global__ __launch_bounds__(256)
void repack_weights(const float* __restrict__ W, const float* __restrict__ Uw,
                    int K1, int K, ushort_t* __restrict__ out)
{
    const int nkb = K >> 5;
    const int kb = blockIdx.x % nkb;
    const int nb = blockIdx.x / nkb;
    __shared__ ushort_t tile[2048];
    const int tid = threadIdx.x;
#pragma unroll
    for (int i = 0; i < 8; i++) {
        int idx  = tid + (i << 8);         // 0..2047
        int kl   = idx >> 6;               // 0..31
        int lcol = idx & 63;               // 0..63
        int g  = lcol >> 4;
        int jl = lcol & 15;
        int k  = (kb << 5) + kl;
        int n_old = (g << 10) + (nb << 4) + jl;
        float v = (k < K1) ? W[(long)k * kG + n_old]
                           : Uw[(long)(k - K1) * kG + n_old];
        int n_new_l = (jl << 2) + g;       // local packed column
        int ng = n_new_l >> 4, nl = n_new_l & 15;
        int quad = kl >> 3, e = kl & 7;
        tile[ng * 512 + (quad * 16 + nl) * 8 + e] = f2bf(v);
    }
    __syncthreads();
    long base = ((long)(nb * nkb + kb)) * 2048;
    *(frag8*)&out[base + tid * 8] = *(frag8*)&tile[tid * 8];
}

__global__ __launch_bounds__(256)
void repack_bias(const float* __restrict__ b1, const float* __restrict__ b2,
                 float* __restrict__ o1, float* __restrict__ o2)
{
    int n = blockIdx.x * blockDim.x + threadIdx.x;   // 0..4095
    int n_old = ((n & 3) << 10) + (n >> 2);
    o1[n] = b1[n_old];
    o2[n] = b2[n_old];
}

// One-time embedding gather + fp32->bf16: xbf[b*T+t][d].
__global__ __launch_bounds__(128)
void xgather(const int* __restrict__ tokens, const float* __restrict__ emb,
             ushort_t* __restrict__ xbf)
{
    int bt = blockIdx.x;
    int tok = tokens[bt];
    float4 v = *(const float4*)(emb + (long)tok * kD + threadIdx.x * 4);
    unsigned int lo = ((unsigned int)f2bf(v.y) << 16) | f2bf(v.x);
    unsigned int hi = ((unsigned int)f2bf(v.w) << 16) | f2bf(v.z);
    uint2 p; p.x = lo; p.y = hi;
    *(uint2*)(xbf + (long)bt * kD + threadIdx.x * 4) = p;
}

// ---------------------------------------------------------------------------
// Per-step kernel. Grid (64,4,2) x 256 thr, __launch_bounds__(256,2):
// 512 blocks, 2 blocks/CU (VGPR <= 256, no spill — round 3's 112-VGPR spill
// was the regression). Block = 64 packed cols (blockIdx.x) x 64 rows
// (blockIdx.y). 4 waves in 2x2; wave tile 32 rows x 32 cols, acc[2][2].
// B staged global->LDS in 16 KB 4-kb chunks via global_load_lds (no VGPR
// round-trip), double-buffered, one barrier per chunk; A register-prefetched
// one chunk ahead. Second resident block covers barrier/latency stalls.
// Same per-element kb accumulation order as round 0 -> bitwise-identical.
// ---------------------------------------------------------------------------
template<int NKB, int K1KB>
__device__ __forceinline__ void step_core(
    const ushort_t* __restrict__ A1, long a1_rs, long a1_off,
    const ushort_t* __restrict__ A2,              // row stride kU
    const ushort_t* __restrict__ Wp,
    const float4* __restrict__ biasP4,
    float* __restrict__ cSt, ushort_t* __restrict__ hOut,
    ushort_t* __restrict__ bl, float* __restrict__ zsw)
{
    const int tid  = threadIdx.x;
    const int lane = tid & 63;
    const int wave = tid >> 6;
    const int wr   = wave >> 1, wc = wave & 1;     // 2x2 wave grid
    const int cb   = blockIdx.x;                   // 64-col superblock 0..63
    const int wrow = (blockIdx.y << 6) + (wr << 5);
    const int kq   = (lane >> 4) << 3;
    const int r0   = wrow + (lane & 15);

    const ushort_t* a1p0 = A1 + (long)r0 * a1_rs + a1_off + kq;
    const ushort_t* a1p1 = A1 + (long)(r0 + 16) * a1_rs + a1_off + kq;
    const ushort_t* a2p0 = A2 + (long)r0 * kU + kq;
    const ushort_t* a2p1 = A2 + (long)(r0 + 16) * kU + kq;

    // weights for this cb: NKB*2048 ushorts; chunk = 4 kb = 8192 ushorts (16KB)
    const ushort_t* Wg = Wp + (long)cb * NKB * 2048;
    constexpr int NCH = NKB / 4;                   // 16 (L2) / 12 (L1) — even

    floatx4 acc[2][2];
#pragma unroll
    for (int i = 0; i < 2; i++) {
        acc[i][0] = (floatx4){0.f, 0.f, 0.f, 0.f};
        acc[i][1] = (floatx4){0.f, 0.f, 0.f, 0.f};
    }

    auto stage = [&](int ch, int p) {              // 16 KB linear copy -> LDS
        const ushort_t* gs = Wg + (long)ch * 8192;
        ushort_t* ls = bl + p * 8192;
#pragma unroll
        for (int j = 0; j < 4; j++) {
            int off = j * 2048 + tid * 8;
            gl_lds16(gs + off, ls + off);
        }
    };

    auto ldA = [&](int ch, frag8 (&d)[8]) {
        const int kb0 = ch * 4;
        if (kb0 < K1KB) {                          // chunks are 4-kb aligned
#pragma unroll
            for (int u = 0; u < 4; u++) {
                d[u*2+0] = *(const frag8*)(a1p0 + (kb0 + u) * 32);
                d[u*2+1] = *(const frag8*)(a1p1 + (kb0 + u) * 32);
            }
        } else {
#pragma unroll
            for (int u = 0; u < 4; u++) {
                d[u*2+0] = *(const frag8*)(a2p0 + (kb0 - K1KB + u) * 32);
                d[u*2+1] = *(const frag8*)(a2p1 + (kb0 - K1KB + u) * 32);
            }
        }
    };

    auto compute = [&](int p, frag8 (&a)[8]) {
        const ushort_t* bp = bl + p * 8192;
#pragma unroll
        for (int u = 0; u < 4; u++) {
            frag8 b0 = *(const frag8*)&bp[(((u << 2) + (wc << 1) + 0) * 64 + lane) * 8];
            frag8 b1 = *(const frag8*)&bp[(((u << 2) + (wc << 1) + 1) * 64 + lane) * 8];
#pragma unroll
            for (int mi = 0; mi < 2; mi++) {
                acc[mi][0] = __builtin_amdgcn_mfma_f32_16x16x32_bf16(a[u*2+mi], b0, acc[mi][0], 0, 0, 0);
                acc[mi][1] = __builtin_amdgcn_mfma_f32_16x16x32_bf16(a[u*2+mi], b1, acc[mi][1], 0, 0, 0);
            }
        }
    };

    frag8 aX[8], aY[8];
    stage(0, 0); ldA(0, aX);
    __syncthreads();                               // chunk 0 in LDS (vmcnt 0)
#pragma unroll 1
    for (int c = 0; c < NCH; c += 2) {
        stage(c + 1, 1); ldA(c + 1, aY);           // c+1 < NCH always (even NCH)
        compute(0, aX);
        __syncthreads();                           // buf1 ready, buf0 free
        if (c + 2 < NCH) { stage(c + 2, 0); ldA(c + 2, aX); }
        compute(1, aY);
        __syncthreads();                           // buf0 ready, buf1 free
    }

    // Epilogue: per-wave LDS transpose (intra-wave DS ordering), gates fp32.
    // 32-col variant verified bit-exact in rounds 1-2; c-state global (round 0).
    const int q = lane >> 4, c16 = lane & 15;
    const int rl0 = lane >> 3, jl = lane & 7;      // jl constant per lane
    const int ub = (cb << 4) + (wc << 3);          // h-unit column base
    const float4 bv = biasP4[ub + jl];
#pragma unroll
    for (int mi = 0; mi < 2; mi++) {
#pragma unroll
        for (int ci = 0; ci < 2; ci++)
#pragma unroll
            for (int r = 0; r < 4; r++)
                zsw[((q << 2) + r) * 36 + (ci << 4) + c16] = acc[mi][ci][r];
#pragma unroll
        for (int ii = 0; ii < 2; ii++) {
            int rowl = rl0 + (ii << 3);
            float4 z4 = *(float4*)&zsw[rowl * 36 + (jl << 2)];
            float zi = z4.x + bv.x, zf = z4.y + bv.y;
            float zg = z4.z + bv.z, zo = z4.w + bv.w;
            float ig = 1.f / (1.f + __expf(-zi));
            float fg = 1.f / (1.f + __expf(-zf));
            float og = 1.f / (1.f + __expf(-zo));
            float gg = 1.f - 2.f / (__expf(2.f * zg) + 1.f);   // tanh
            int m = wrow + (mi << 4) + rowl;
            long cidx = (long)m * kU + ub + jl;
            float cn = fg * cSt[cidx] + ig * gg;
            float tc = 1.f - 2.f / (__expf(2.f * cn) + 1.f);   // tanh
            cSt[cidx] = cn;
            hOut[cidx] = f2bf(og * tc);
        }
    }
}

// grid (64, 4, 2): z=0 -> layer2 step t2=l-1, z=1 -> layer1 step t1=l
__global__ __launch_bounds__(256, 2)
void lstm_merged(int zmask,
    const ushort_t* h1_for2, const ushort_t* h2prev, const ushort_t* W2p,
    const float* b2p, float* c2, ushort_t* h2out,
    const ushort_t* xbf, int t1,
    const ushort_t* h1prev, const ushort_t* W1p,
    const float* b1p, float* c1, ushort_t* h1out)
{
    __shared__ __align__(16) ushort_t bl[16384];   // 32 KB B double-buffer
    __shared__ __align__(16) float zs[4][576];     // 9 KB epilogue transpose
    float* zsw = zs[threadIdx.x >> 6];
    if (blockIdx.z == 0) {
        if (!(zmask & 1)) return;
        step_core<64, 32>(h1_for2, kU, 0, h2prev, W2p,
                          (const float4*)b2p, c2, h2out, bl, zsw);
    } else {
        if (!(zmask & 2)) return;
        step_core<48, 16>(xbf, (long)kT * kD, (long)t1 * kD, h1prev, W1p,
                          (const float4*)b1p, c1, h1out, bl, zsw);
    }
}

// out[b] = sigmoid(h[b,:] . Wfc + bfc), h in bf16
__global__ __launch_bounds__(256)
void fc_sigmoid(const ushort_t* __restrict__ h, const float* __restrict__ Wfc,
                const float* __restrict__ bfc, float* __restrict__ out)
{
    int b = blockIdx.x, tid = threadIdx.x;
    float s = 0.f;
    for (int j = tid; j < kU; j += 256) s += bf2f(h[(long)b * kU + j]) * Wfc[j];
    __shared__ float red[4];
    for (int off = 32; off > 0; off >>= 1) s += __shfl_down(s, off, 64);
    if ((tid & 63) == 0) red[tid >> 6] = s;
    __syncthreads();
    if (tid == 0) {
        float t = red[0] + red[1] + red[2] + red[3] + bfc[0];
        out[b] = 1.f / (1.f + expf(-t));
    }
}

extern "C" void kernel_launch(void* const* d_in, const int* in_sizes, int n_in,
                              void* d_out, int out_size, void* d_ws, size_t ws_size,
                              hipStream_t stream)
{
    (void)in_sizes; (void)n_in; (void)out_size; (void)ws_size;

    const int*   tokens = (const int*)d_in[0];
    const float* emb    = (const float*)d_in[1];
    const float* W1     = (const float*)d_in[2];
    const float* U1     = (const float*)d_in[3];
    const float* b1     = (const float*)d_in[4];
    const float* W2     = (const float*)d_in[5];
    const float* U2     = (const float*)d_in[6];
    const float* b2     = (const float*)d_in[7];
    const float* Wfc    = (const float*)d_in[8];
    const float* bfc    = (const float*)d_in[9];
    float* out = (float*)d_out;

    // Workspace: ~86 MB
    ushort_t* W1p = (ushort_t*)d_ws;                       // [1536*4096] bf16
    ushort_t* W2p = W1p + (size_t)1536 * kG;               // [2048*4096] bf16
    float* b1p = (float*)(W2p + (size_t)2048 * kG);        // [4096] f32
    float* b2p = b1p + kG;                                 // [4096] f32
    float* c1  = b2p + kG;                                 // [256*1024] f32
    float* c2  = c1 + (size_t)kB * kU;
    ushort_t* hbuf = (ushort_t*)(c2 + (size_t)kB * kU);    // 4 x [256*1024] bf16
    ushort_t* h1b[2] = { hbuf, hbuf + (size_t)kB * kU };
    ushort_t* h2b[2] = { hbuf + 2 * (size_t)kB * kU, hbuf + 3 * (size_t)kB * kU };
    ushort_t* xbf = hbuf + 4 * (size_t)kB * kU;            // [B*T*512] bf16

    repack_weights<<<48 * 64, 256, 0, stream>>>(W1, U1, 512, 1536, W1p);
    repack_weights<<<64 * 64, 256, 0, stream>>>(W2, U2, 1024, 2048, W2p);
    repack_bias<<<16, 256, 0, stream>>>(b1, b2, b1p, b2p);
    xgather<<<kB * kT, 128, 0, stream>>>(tokens, emb, xbf);
    // zero c1,c2 (fp32) + all h buffers (bf16): contiguous 4 MB
    hipMemsetAsync(c1, 0, (size_t)kB * kU * (2 * 4 + 4 * 2), stream);

    for (int l = 0; l <= kT; l++) {
        int t2 = l - 1, t1 = l;
        int zmask = (t2 >= 0 ? 1 : 0) | (t1 < kT ? 2 : 0);
        lstm_merged<<<dim3(64, 4, 2), 256, 0, stream>>>(zmask,
            h1b[(t2 + 1) & 1], h2b[t2 & 1], W2p, b2p, c2, h2b[(t2 + 1) & 1],
            xbf, t1, h1b[t1 & 1], W1p, b1p, c1, h1b[(t1 + 1) & 1]);
    }

    fc_sigmoid<<<kB, 256, 0, stream>>>(h2b[0], Wfc, bfc, out);
}

// Round 5
// 6954.922 us; speedup vs baseline: 1.8295x; 1.0722x over previous
//
#include <hip/hip_runtime.h>
#include <math.h>

constexpr int kB = 256;
constexpr int kT = 200;
constexpr int kD = 512;
constexpr int kU = 1024;
constexpr int kG = 4096;   // 4*U

typedef short frag8 __attribute__((ext_vector_type(8)));     // 8 bf16 (4 VGPRs)
typedef float floatx4 __attribute__((ext_vector_type(4)));   // MFMA C/D frag
typedef unsigned short ushort_t;

typedef __attribute__((address_space(1))) const unsigned int as1_uint;
typedef __attribute__((address_space(3))) unsigned int as3_uint;

__device__ __forceinline__ ushort_t f2bf(float f) {
    union { float f; unsigned int u; } v; v.f = f;
    unsigned int r = v.u + 0x7fffu + ((v.u >> 16) & 1u);   // RNE
    return (ushort_t)(r >> 16);
}
__device__ __forceinline__ float bf2f(ushort_t h) {
    union { unsigned int u; float f; } v; v.u = ((unsigned int)h) << 16;
    return v.f;
}

// global -> LDS direct copy, 16B per lane. LDS dest = wave-uniform base +
// lane*16 (per-lane l pointer is lane-linear).
__device__ __forceinline__ void gl_lds16(const ushort_t* g, ushort_t* l) {
    __builtin_amdgcn_global_load_lds((as1_uint*)g, (as3_uint*)l, 16, 0, 0);
}

// ---------------------------------------------------------------------------
// Repack [W (K1 rows); Uw (K-K1 rows)] fp32 [*,4096] -> bf16 fragment order.
// Gate-interleaved columns: n_new = 4*j + g  <->  n_old = g*1024 + j.
// frag8 addr (units): ((nb*nkb + kb)*4 + ct)*64 + lane  (verified, absmax 0.0)
// For each 64-col supergroup nb, an 8-kb chunk (32 KB) is CONTIGUOUS.
// ---------------------------------------------------------------------------
__global__ __launch_bounds__(256)
void repack_weights(const float* __restrict__ W, const float* __restrict__ Uw,
                    int K1, int K, ushort_t* __restrict__ out)
{
    const int nkb = K >> 5;
    const int kb = blockIdx.x % nkb;
    const int nb = blockIdx.x / nkb;
    __shared__ ushort_t tile[2048];
    const int tid = threadIdx.x;
#pragma unroll
    for (int i = 0; i < 8; i++) {
        int idx  = tid + (i << 8);         // 0..2047
        int kl   = idx >> 6;               // 0..31
        int lcol = idx & 63;               // 0..63
        int g  = lcol >> 4;
        int jl = lcol & 15;
        int k  = (kb << 5) + kl;
        int n_old = (g << 10) + (nb << 4) + jl;
        float v = (k < K1) ? W[(long)k * kG + n_old]
                           : Uw[(long)(k - K1) * kG + n_old];
        int n_new_l = (jl << 2) + g;       // local packed column
        int ng = n_new_l >> 4, nl = n_new_l & 15;
        int quad = kl >> 3, e = kl & 7;
        tile[ng * 512 + (quad * 16 + nl) * 8 + e] = f2bf(v);
    }
    __syncthreads();
    long base = ((long)(nb * nkb + kb)) * 2048;
    *(frag8*)&out[base + tid * 8] = *(frag8*)&tile[tid * 8];
}

__global__ __launch_bounds__(256)
void repack_bias(const float* __restrict__ b1, const float* __restrict__ b2,
                 float* __restrict__ o1, float* __restrict__ o2)
{
    int n = blockIdx.x * blockDim.x + threadIdx.x;   // 0..4095
    int n_old = ((n & 3) << 10) + (n >> 2);
    o1[n] = b1[n_old];
    o2[n] = b2[n_old];
}

// One-time embedding gather + fp32->bf16: xbf[b*T+t][d].
__global__ __launch_bounds__(128)
void xgather(const int* __restrict__ tokens, const float* __restrict__ emb,
             ushort_t* __restrict__ xbf)
{
    int bt = blockIdx.x;
    int tok = tokens[bt];
    float4 v = *(const float4*)(emb + (long)tok * kD + threadIdx.x * 4);
    unsigned int lo = ((unsigned int)f2bf(v.y) << 16) | f2bf(v.x);
    unsigned int hi = ((unsigned int)f2bf(v.w) << 16) | f2bf(v.z);
    uint2 p; p.x = lo; p.y = hi;
    *(uint2*)(xbf + (long)bt * kD + threadIdx.x * 4) = p;
}

// ---------------------------------------------------------------------------
// Per-step kernel. Grid (64,4,2) x 256 thr, __launch_bounds__(256,2):
// 512 blocks, 2 blocks/CU — dispatch order puts one layer2 + one layer1 block
// on each CU (cross-layer TLP: one block computes while the other drains).
// Block = 64 packed cols (blockIdx.x) x 64 rows (blockIdx.y); 4 waves 2x2,
// wave tile 32x32 (acc[2][2], round-4-verified epilogue).
// vs round 4: chunk size 4kb -> 8kb (32 KB B slab). Halves the barrier count
// (8+6 per step vs 16+12) and doubles compute per barrier window (32 MFMA +
// 16 ds_read_b128), so the compiler's vmcnt(0) drain before each s_barrier is
// amortized over 2x the work. A is double-buffered one full chunk ahead in
// registers (aX/aY[16] = 128 VGPR; total ~190 < 256 cap -> no spill).
// Same per-element kb accumulation order as round 0 -> bitwise-identical.
// ---------------------------------------------------------------------------
template<int NKB, int K1KB>
__device__ __forceinline__ void step_core(
    const ushort_t* __restrict__ A1, long a1_rs, long a1_off,
    const ushort_t* __restrict__ A2,              // row stride kU
    const ushort_t* __restrict__ Wp,
    const float4* __restrict__ biasP4,
    float* __restrict__ cSt, ushort_t* __restrict__ hOut,
    ushort_t* __restrict__ bl, float* __restrict__ zsw)
{
    const int tid  = threadIdx.x;
    const int lane = tid & 63;
    const int wave = tid >> 6;
    const int wr   = wave >> 1, wc = wave & 1;     // 2x2 wave grid
    const int cb   = blockIdx.x;                   // 64-col superblock 0..63
    const int wrow = (blockIdx.y << 6) + (wr << 5);
    const int kq   = (lane >> 4) << 3;
    const int r0   = wrow + (lane & 15);

    const ushort_t* a1p0 = A1 + (long)r0 * a1_rs + a1_off + kq;
    const ushort_t* a1p1 = A1 + (long)(r0 + 16) * a1_rs + a1_off + kq;
    const ushort_t* a2p0 = A2 + (long)r0 * kU + kq;
    const ushort_t* a2p1 = A2 + (long)(r0 + 16) * kU + kq;

    // weights for this cb: NKB*2048 ushorts; chunk = 8 kb = 16384 ushorts (32KB)
    const ushort_t* Wg = Wp + (long)cb * NKB * 2048;
    constexpr int NCH = NKB / 8;                   // 8 (L2) / 6 (L1) — even
    static_assert(K1KB % 8 == 0, "chunks must not straddle the A1/A2 boundary");

    floatx4 acc[2][2];
#pragma unroll
    for (int i = 0; i < 2; i++) {
        acc[i][0] = (floatx4){0.f, 0.f, 0.f, 0.f};
        acc[i][1] = (floatx4){0.f, 0.f, 0.f, 0.f};
    }

    auto stage = [&](int ch, int p) {              // 32 KB linear copy -> LDS
        const ushort_t* gs = Wg + (long)ch * 16384;
        ushort_t* ls = bl + p * 16384;
#pragma unroll
        for (int j = 0; j < 8; j++) {
            int off = j * 2048 + tid * 8;
            gl_lds16(gs + off, ls + off);
        }
    };

    auto ldA = [&](int ch, frag8 (&d)[16]) {
        const int kb0 = ch * 8;
        const ushort_t* p0;
        const ushort_t* p1;
        if (kb0 < K1KB) { p0 = a1p0 + kb0 * 32;          p1 = a1p1 + kb0 * 32; }
        else            { p0 = a2p0 + (kb0 - K1KB) * 32; p1 = a2p1 + (kb0 - K1KB) * 32; }
#pragma unroll
        for (int u = 0; u < 8; u++) {
            d[u*2+0] = *(const frag8*)(p0 + u * 32);
            d[u*2+1] = *(const frag8*)(p1 + u * 32);
        }
    };

    auto compute = [&](int p, frag8 (&a)[16]) {
        const ushort_t* bp = bl + p * 16384;
#pragma unroll
        for (int u = 0; u < 8; u++) {
            frag8 b0 = *(const frag8*)&bp[(((u << 2) + (wc << 1) + 0) * 64 + lane) * 8];
            frag8 b1 = *(const frag8*)&bp[(((u << 2) + (wc << 1) + 1) * 64 + lane) * 8];
#pragma unroll
            for (int mi = 0; mi < 2; mi++) {
                acc[mi][0] = __builtin_amdgcn_mfma_f32_16x16x32_bf16(a[u*2+mi], b0, acc[mi][0], 0, 0, 0);
                acc[mi][1] = __builtin_amdgcn_mfma_f32_16x16x32_bf16(a[u*2+mi], b1, acc[mi][1], 0, 0, 0);
            }
        }
    };

    frag8 aX[16], aY[16];
    stage(0, 0); ldA(0, aX);
    __syncthreads();                               // chunk 0 in LDS (vmcnt 0)
#pragma unroll 1
    for (int c = 0; c < NCH; c += 2) {
        stage(c + 1, 1); ldA(c + 1, aY);           // c+1 < NCH always (even NCH)
        compute(0, aX);
        __syncthreads();                           // buf1 ready, buf0 free
        if (c + 2 < NCH) { stage(c + 2, 0); ldA(c + 2, aX); }
        compute(1, aY);
        __syncthreads();                           // buf0 ready, buf1 free
    }

    // Epilogue: per-wave LDS transpose (intra-wave DS ordering), gates fp32.
    // Verified bit-exact (rounds 1-4); c-state global (round 0).
    const int q = lane >> 4, c16 = lane & 15;
    const int rl0 = lane >> 3, jl = lane & 7;      // jl constant per lane
    const int ub = (cb << 4) + (wc << 3);          // h-unit column base
    const float4 bv = biasP4[ub + jl];
#pragma unroll
    for (int mi = 0; mi < 2; mi++) {
#pragma unroll
        for (int ci = 0; ci < 2; ci++)
#pragma unroll
            for (int r = 0; r < 4; r++)
                zsw[((q << 2) + r) * 36 + (ci << 4) + c16] = acc[mi][ci][r];
#pragma unroll
        for (int ii = 0; ii < 2; ii++) {
            int rowl = rl0 + (ii << 3);
            float4 z4 = *(float4*)&zsw[rowl * 36 + (jl << 2)];
            float zi = z4.x + bv.x, zf = z4.y + bv.y;
            float zg = z4.z + bv.z, zo = z4.w + bv.w;
            float ig = 1.f / (1.f + __expf(-zi));
            float fg = 1.f / (1.f + __expf(-zf));
            float og = 1.f / (1.f + __expf(-zo));
            float gg = 1.f - 2.f / (__expf(2.f * zg) + 1.f);   // tanh
            int m = wrow + (mi << 4) + rowl;
            long cidx = (long)m * kU + ub + jl;
            float cn = fg * cSt[cidx] + ig * gg;
            float tc = 1.f - 2.f / (__expf(2.f * cn) + 1.f);   // tanh
            cSt[cidx] = cn;
            hOut[cidx] = f2bf(og * tc);
        }
    }
}

// grid (64, 4, 2): z=0 -> layer2 step t2=l-1, z=1 -> layer1 step t1=l
__global__ __launch_bounds__(256, 2)
void lstm_merged(int zmask,
    const ushort_t* h1_for2, const ushort_t* h2prev, const ushort_t* W2p,
    const float* b2p, float* c2, ushort_t* h2out,
    const ushort_t* xbf, int t1,
    const ushort_t* h1prev, const ushort_t* W1p,
    const float* b1p, float* c1, ushort_t* h1out)
{
    __shared__ __align__(16) ushort_t bl[32768];   // 64 KB B double-buffer
    __shared__ __align__(16) float zs[4][576];     // 9 KB epilogue transpose
    float* zsw = zs[threadIdx.x >> 6];
    if (blockIdx.z == 0) {
        if (!(zmask & 1)) return;
        step_core<64, 32>(h1_for2, kU, 0, h2prev, W2p,
                          (const float4*)b2p, c2, h2out, bl, zsw);
    } else {
        if (!(zmask & 2)) return;
        step_core<48, 16>(xbf, (long)kT * kD, (long)t1 * kD, h1prev, W1p,
                          (const float4*)b1p, c1, h1out, bl, zsw);
    }
}

// out[b] = sigmoid(h[b,:] . Wfc + bfc), h in bf16
__global__ __launch_bounds__(256)
void fc_sigmoid(const ushort_t* __restrict__ h, const float* __restrict__ Wfc,
                const float* __restrict__ bfc, float* __restrict__ out)
{
    int b = blockIdx.x, tid = threadIdx.x;
    float s = 0.f;
    for (int j = tid; j < kU; j += 256) s += bf2f(h[(long)b * kU + j]) * Wfc[j];
    __shared__ float red[4];
    for (int off = 32; off > 0; off >>= 1) s += __shfl_down(s, off, 64);
    if ((tid & 63) == 0) red[tid >> 6] = s;
    __syncthreads();
    if (tid == 0) {
        float t = red[0] + red[1] + red[2] + red[3] + bfc[0];
        out[b] = 1.f / (1.f + expf(-t));
    }
}

extern "C" void kernel_launch(void* const* d_in, const int* in_sizes, int n_in,
                              void* d_out, int out_size, void* d_ws, size_t ws_size,
                              hipStream_t stream)
{
    (void)in_sizes; (void)n_in; (void)out_size; (void)ws_size;

    const int*   tokens = (const int*)d_in[0];
    const float* emb    = (const float*)d_in[1];
    const float* W1     = (const float*)d_in[2];
    const float* U1     = (const float*)d_in[3];
    const float* b1     = (const float*)d_in[4];
    const float* W2     = (const float*)d_in[5];
    const float* U2     = (const float*)d_in[6];
    const float* b2     = (const float*)d_in[7];
    const float* Wfc    = (const float*)d_in[8];
    const float* bfc    = (const float*)d_in[9];
    float* out = (float*)d_out;

    // Workspace: ~86 MB
    ushort_t* W1p = (ushort_t*)d_ws;                       // [1536*4096] bf16
    ushort_t* W2p = W1p + (size_t)1536 * kG;               // [2048*4096] bf16
    float* b1p = (float*)(W2p + (size_t)2048 * kG);        // [4096] f32
    float* b2p = b1p + kG;                                 // [4096] f32
    float* c1  = b2p + kG;                                 // [256*1024] f32
    float* c2  = c1 + (size_t)kB * kU;
    ushort_t* hbuf = (ushort_t*)(c2 + (size_t)kB * kU);    // 4 x [256*1024] bf16
    ushort_t* h1b[2] = { hbuf, hbuf + (size_t)kB * kU };
    ushort_t* h2b[2] = { hbuf + 2 * (size_t)kB * kU, hbuf + 3 * (size_t)kB * kU };
    ushort_t* xbf = hbuf + 4 * (size_t)kB * kU;            // [B*T*512] bf16

    repack_weights<<<48 * 64, 256, 0, stream>>>(W1, U1, 512, 1536, W1p);
    repack_weights<<<64 * 64, 256, 0, stream>>>(W2, U2, 1024, 2048, W2p);
    repack_bias<<<16, 256, 0, stream>>>(b1, b2, b1p, b2p);
    xgather<<<kB * kT, 128, 0, stream>>>(tokens, emb, xbf);
    // zero c1,c2 (fp32) + all h buffers (bf16): contiguous 4 MB
    hipMemsetAsync(c1, 0, (size_t)kB * kU * (2 * 4 + 4 * 2), stream);

    for (int l = 0; l <= kT; l++) {
        int t2 = l - 1, t1 = l;
        int zmask = (t2 >= 0 ? 1 : 0) | (t1 < kT ? 2 : 0);
        lstm_merged<<<dim3(64, 4, 2), 256, 0, stream>>>(zmask,
            h1b[(t2 + 1) & 1], h2b[t2 & 1], W2p, b2p, c2, h2b[(t2 + 1) & 1],
            xbf, t1, h1b[t1 & 1], W1p, b1p, c1, h1b[(t1 + 1) & 1]);
    }

    fc_sigmoid<<<kB, 256, 0, stream>>>(h2b[0], Wfc, bfc, out);
}